// Round 3
// baseline (2863.527 us; speedup 1.0000x reference)
//
#include <hip/hip_runtime.h>
#include <hip/hip_fp16.h>

#define N_NODES 100000
#define N_EDGES 1600000
#define IN_F 32
#define HID 128
#define BSHIFT 9
#define BSIZE 512
#define NBUCK 196       // ceil(100000/512)
#define EPB 8192        // edges per bucket-phase block
#define NBB 196         // ceil(E/EPB)
#define NSH 10          // source shards (phases); slice = ~10k rows
#define GGRID 2048      // gather grid: 8 blocks/CU co-resident
#define GW (GGRID * 4)  // gather waves = 8192
#define NPW 13          // ceil(N_NODES / GW) nodes per wave

typedef _Float16 half8 __attribute__((ext_vector_type(8)));
typedef float floatx4 __attribute__((ext_vector_type(4)));

static __device__ __forceinline__ void pack2(_Float16* dst, float a, float b) {
    union { _Float16 h[2]; unsigned u; } p;
    p.h[0] = (_Float16)a; p.h[1] = (_Float16)b;
    *(unsigned*)dst = p.u;
}

static __device__ __forceinline__ int shard_of(int src) {
    // maps [0,100000) -> [0,10): floor(src / 10082.46...)
    return (int)(((unsigned)src * 26u) >> 18);
}

// soft phase barrier: per-group (bid&7 ~ XCD) counters, bounded spin.
// Correctness never depends on it (pure L2-phase-alignment hint).
static __device__ __forceinline__ void phase_barrier(int* c) {
    __syncthreads();
    if (threadIdx.x == 0) {
        atomicAdd(c, 1);
        long long t0 = clock64();
        while (__hip_atomic_load(c, __ATOMIC_RELAXED, __HIP_MEMORY_SCOPE_AGENT)
               < GGRID / 8) {
            __builtin_amdgcn_s_sleep(2);
            if (clock64() - t0 > 20000) break;   // ~8 us cap
        }
    }
    __syncthreads();
}

// ---------------- CSR build (bucketed, no global per-node atomics) ----------------

__global__ __launch_bounds__(256) void k_bcount(const int* __restrict__ dst,
                                                int* __restrict__ bcnt) {
    __shared__ int hist[256];
    hist[threadIdx.x] = 0;
    __syncthreads();
    const int e0 = blockIdx.x * EPB;
#pragma unroll 4
    for (int k = 0; k < 32; ++k) {
        int e = e0 + k * 256 + threadIdx.x;
        if (e < N_EDGES) atomicAdd(&hist[dst[e] >> BSHIFT], 1);
    }
    __syncthreads();
    int c = hist[threadIdx.x];
    if (c > 0) atomicAdd(&bcnt[threadIdx.x], c);
}

__global__ __launch_bounds__(256) void k_bscan(const int* __restrict__ bcnt,
                                               int* __restrict__ bbase,
                                               int* __restrict__ bcur) {
    __shared__ int s[256];
    int v = (threadIdx.x < NBUCK) ? bcnt[threadIdx.x] : 0;
    s[threadIdx.x] = v;
    __syncthreads();
    for (int off = 1; off < 256; off <<= 1) {
        int t = (threadIdx.x >= off) ? s[threadIdx.x - off] : 0;
        __syncthreads();
        s[threadIdx.x] += t;
        __syncthreads();
    }
    if (threadIdx.x < NBUCK) {
        int ex = s[threadIdx.x] - v;
        bbase[threadIdx.x] = ex;
        bcur[threadIdx.x]  = ex;
    }
    if (threadIdx.x == 0) bbase[NBUCK] = N_EDGES;
}

__global__ __launch_bounds__(256) void k_bucket(const int* __restrict__ src,
                                                const int* __restrict__ dst,
                                                int* __restrict__ bcur,
                                                unsigned* __restrict__ rec) {
    __shared__ int hist[256];
    __shared__ int lbase[256];
    const int e0 = blockIdx.x * EPB;
    hist[threadIdx.x] = 0;
    __syncthreads();

    unsigned rk[32]; short bk[32];
#pragma unroll
    for (int k = 0; k < 32; ++k) {
        int e = e0 + k * 256 + threadIdx.x;
        if (e < N_EDGES) {
            int d = dst[e];
            int b = d >> BSHIFT;
            bk[k] = (short)b;
            rk[k] = ((unsigned)src[e] << BSHIFT) | (unsigned)(d & (BSIZE - 1));
            atomicAdd(&hist[b], 1);
        } else bk[k] = -1;
    }
    __syncthreads();
    int c = hist[threadIdx.x];
    lbase[threadIdx.x] = (c > 0) ? atomicAdd(&bcur[threadIdx.x], c) : 0;
    __syncthreads();
    hist[threadIdx.x] = 0;   // reuse as local running offset
    __syncthreads();
#pragma unroll
    for (int k = 0; k < 32; ++k) {
        if (bk[k] >= 0) {
            int off = atomicAdd(&hist[bk[k]], 1);
            rec[lbase[bk[k]] + off] = rk[k];
        }
    }
}

// per bucket: count per (shard,node), scan 5120 counters, emit packed seg
// (start<<5 | count) per (node,shard) and scatter col SHARD-MAJOR so each
// gather phase reads a contiguous col region.
__global__ __launch_bounds__(256) void k_fill3(const unsigned* __restrict__ rec,
                                               const int* __restrict__ bbase,
                                               int* __restrict__ ideg,
                                               unsigned* __restrict__ seg,
                                               int* __restrict__ col) {
    __shared__ int lcnt[BSIZE * NSH];   // [shard][node] 20 KB
    __shared__ int lcur[BSIZE * NSH];   // 20 KB
    __shared__ int s[256];
    const int b = blockIdx.x;
    const int n0 = b << BSHIFT;
    const int rbeg = bbase[b];
    const int rend = bbase[b + 1];
    const int t = threadIdx.x;

    for (int i = t; i < BSIZE * NSH; i += 256) lcnt[i] = 0;
    __syncthreads();
    for (int i = rbeg + t; i < rend; i += 256) {
        unsigned r = rec[i];
        int sr = (int)(r >> BSHIFT), loc = (int)(r & (BSIZE - 1));
        atomicAdd(&lcnt[shard_of(sr) * BSIZE + loc], 1);
    }
    __syncthreads();

    // block scan over 5120 counters; thread owns 20 consecutive
    const int base = t * 20;
    int sum = 0;
#pragma unroll
    for (int k = 0; k < 20; ++k) sum += lcnt[base + k];
    s[t] = sum;
    __syncthreads();
    for (int off = 1; off < 256; off <<= 1) {
        int v = (t >= off) ? s[t - off] : 0;
        __syncthreads();
        s[t] += v;
        __syncthreads();
    }
    int run = rbeg + s[t] - sum;
#pragma unroll
    for (int k = 0; k < 20; ++k) { lcur[base + k] = run; run += lcnt[base + k]; }
    __syncthreads();

    // emit seg + ideg (2 nodes per thread)
#pragma unroll
    for (int h = 0; h < 2; ++h) {
        int loc = 2 * t + h, n = n0 + loc;
        if (n < N_NODES) {
            int deg = 0;
#pragma unroll
            for (int sh = 0; sh < NSH; ++sh) {
                int c = lcnt[sh * BSIZE + loc];
                seg[n * NSH + sh] =
                    ((unsigned)lcur[sh * BSIZE + loc] << 5) | (unsigned)c;
                deg += c;
            }
            ideg[n] = deg;
        }
    }
    __syncthreads();
    for (int i = rbeg + t; i < rend; i += 256) {
        unsigned r = rec[i];
        int sr = (int)(r >> BSHIFT), loc = (int)(r & (BSIZE - 1));
        int slot = atomicAdd(&lcur[shard_of(sr) * BSIZE + loc], 1);
        col[slot] = sr;
    }
}

// ---------------- layer-1 prescale: t1 = x * dis (fp16, 32-dim) ----------------

__global__ void k_prescale(const float2* __restrict__ x, const int* __restrict__ ideg,
                           __half2* __restrict__ T) {
    int tid = blockIdx.x * 256 + threadIdx.x;
    if (tid >= N_NODES * 16) return;
    int i = tid >> 4;
    float dis = rsqrtf(1.0f + (float)ideg[i]);
    float2 v = x[tid];
    T[tid] = __floats2half2_rn(v.x * dis, v.y * dis);
}

// ---------------- sharded phased gathers (acc in registers) ----------------

// 128-dim: lane = feature pair (half2), whole wave per edge row (256B coalesced).
__global__ __launch_bounds__(256, 8) void k_gather128_sh(
    const unsigned* __restrict__ seg, const int* __restrict__ ideg,
    const int* __restrict__ col, const _Float16* __restrict__ T,
    const float* __restrict__ b, _Float16* __restrict__ OUT,
    int* __restrict__ bar) {
    const int lane = threadIdx.x & 63;
    const int wid  = blockIdx.x * 4 + (threadIdx.x >> 6);
    const int grp  = blockIdx.x & 7;

    float a0[NPW], a1[NPW];
#pragma unroll
    for (int j = 0; j < NPW; ++j) {
        int node = wid + j * GW;
        if (node < N_NODES) {
            float2 f = __half22float2(((const __half2*)(T + (size_t)node * HID))[lane]);
            a0[j] = f.x; a1[j] = f.y;
        } else { a0[j] = 0.f; a1[j] = 0.f; }
    }

    for (int p = 0; p < NSH; ++p) {
        if (p) phase_barrier(bar + (p - 1) * 8 + grp);
#pragma unroll
        for (int j = 0; j < NPW; ++j) {
            int node = wid + j * GW;
            if (node < N_NODES) {
                unsigned sc = seg[node * NSH + p];
                int bgn = (int)(sc >> 5), L = (int)(sc & 31u);
                for (int i = 0; i < L; ++i) {
                    int s2 = col[bgn + i];
                    float2 f = __half22float2(
                        ((const __half2*)(T + (size_t)s2 * HID))[lane]);
                    a0[j] += f.x; a1[j] += f.y;
                }
            }
        }
    }

    float2 bb = ((const float2*)b)[lane];
#pragma unroll
    for (int j = 0; j < NPW; ++j) {
        int node = wid + j * GW;
        if (node < N_NODES) {
            float dis = rsqrtf(1.0f + (float)ideg[node]);
            float v0 = a0[j] * dis + bb.x;
            float v1 = a1[j] * dis + bb.y;
            v0 = v0 > 0.f ? v0 : 0.f;
            v1 = v1 > 0.f ? v1 : 0.f;
            ((__half2*)(OUT + (size_t)node * HID))[lane] = __floats2half2_rn(v0, v1);
        }
    }
}

// 32-dim: 2 edge-slots x 32 feature lanes; one shfl merge per node at the end.
// pre: OUT = acc*dis (fp16)
__global__ __launch_bounds__(256, 8) void k_gather32p_sh(
    const unsigned* __restrict__ seg, const int* __restrict__ ideg,
    const int* __restrict__ col, const _Float16* __restrict__ T,
    _Float16* __restrict__ OUT, int* __restrict__ bar) {
    const int lane = threadIdx.x & 63;
    const int fl   = lane & 31;
    const int slot = lane >> 5;
    const int wid  = blockIdx.x * 4 + (threadIdx.x >> 6);
    const int grp  = blockIdx.x & 7;

    float acc[NPW];
#pragma unroll
    for (int j = 0; j < NPW; ++j) {
        int node = wid + j * GW;
        acc[j] = (slot == 0 && node < N_NODES)
                     ? (float)T[(size_t)node * IN_F + fl] : 0.f;
    }

    for (int p = 0; p < NSH; ++p) {
        if (p) phase_barrier(bar + (p - 1) * 8 + grp);
#pragma unroll
        for (int j = 0; j < NPW; ++j) {
            int node = wid + j * GW;
            if (node < N_NODES) {
                unsigned sc = seg[node * NSH + p];
                int bgn = (int)(sc >> 5), L = (int)(sc & 31u);
                for (int i = slot; i < L; i += 2)
                    acc[j] += (float)T[(size_t)col[bgn + i] * IN_F + fl];
            }
        }
    }

#pragma unroll
    for (int j = 0; j < NPW; ++j) {
        int node = wid + j * GW;
        float m = acc[j] + __shfl_xor(acc[j], 32, 64);
        if (lane < 32 && node < N_NODES) {
            float dis = rsqrtf(1.0f + (float)ideg[node]);
            OUT[(size_t)node * IN_F + fl] = (_Float16)(m * dis);
        }
    }
}

// fin: OUT = relu(acc*dis + b) (fp32)
__global__ __launch_bounds__(256, 8) void k_gather32f_sh(
    const unsigned* __restrict__ seg, const int* __restrict__ ideg,
    const int* __restrict__ col, const _Float16* __restrict__ T,
    const float* __restrict__ b, float* __restrict__ OUT,
    int* __restrict__ bar) {
    const int lane = threadIdx.x & 63;
    const int fl   = lane & 31;
    const int slot = lane >> 5;
    const int wid  = blockIdx.x * 4 + (threadIdx.x >> 6);
    const int grp  = blockIdx.x & 7;

    float acc[NPW];
#pragma unroll
    for (int j = 0; j < NPW; ++j) {
        int node = wid + j * GW;
        acc[j] = (slot == 0 && node < N_NODES)
                     ? (float)T[(size_t)node * IN_F + fl] : 0.f;
    }

    for (int p = 0; p < NSH; ++p) {
        if (p) phase_barrier(bar + (p - 1) * 8 + grp);
#pragma unroll
        for (int j = 0; j < NPW; ++j) {
            int node = wid + j * GW;
            if (node < N_NODES) {
                unsigned sc = seg[node * NSH + p];
                int bgn = (int)(sc >> 5), L = (int)(sc & 31u);
                for (int i = slot; i < L; i += 2)
                    acc[j] += (float)T[(size_t)col[bgn + i] * IN_F + fl];
            }
        }
    }

    float bj = b[fl];
#pragma unroll
    for (int j = 0; j < NPW; ++j) {
        int node = wid + j * GW;
        float m = acc[j] + __shfl_xor(acc[j], 32, 64);
        if (lane < 32 && node < N_NODES) {
            float dis = rsqrtf(1.0f + (float)ideg[node]);
            float v = m * dis + bj;
            OUT[(size_t)node * IN_F + fl] = v > 0.f ? v : 0.f;
        }
    }
}

// ---------------- MFMA transforms ----------------
// 16x16x32 layouts: A[m=lane&15][k=quad*8+j], B[k=quad*8+j][n=lane&15],
// D[row=quad*4+r][col=lane&15]. Block = 4 waves x 16 rows = 64 rows.

__global__ __launch_bounds__(256) void k_xform1_mfma(
    const _Float16* __restrict__ z, const float* __restrict__ W,
    const float* __restrict__ bias, _Float16* __restrict__ Hh) {
    __shared__ _Float16 Wt[128 * 40];
    for (int idx = threadIdx.x; idx < 2048; idx += 256) {
        int n = idx & 127, k = (idx >> 7) * 2;
        pack2(&Wt[n * 40 + k], W[k * HID + n], W[(k + 1) * HID + n]);
    }
    __syncthreads();

    const int lane = threadIdx.x & 63;
    const int wave = threadIdx.x >> 6;
    const int m16 = lane & 15, quad = lane >> 4;
    const int row0 = blockIdx.x * 64 + wave * 16;
    if (row0 >= N_NODES) return;

    int arow = row0 + m16; if (arow >= N_NODES) arow = N_NODES - 1;
    half8 a = *(const half8*)(z + (size_t)arow * IN_F + quad * 8);

    floatx4 acc[8];
#pragma unroll
    for (int t = 0; t < 8; ++t) acc[t] = (floatx4){0.f, 0.f, 0.f, 0.f};
#pragma unroll
    for (int t = 0; t < 8; ++t) {
        half8 b = *(const half8*)&Wt[(t * 16 + m16) * 40 + quad * 8];
        acc[t] = __builtin_amdgcn_mfma_f32_16x16x32_f16(a, b, acc[t], 0, 0, 0);
    }
#pragma unroll
    for (int t = 0; t < 8; ++t) {
        int c = t * 16 + m16;
        float bj = bias[c];
#pragma unroll
        for (int r = 0; r < 4; ++r) {
            int row = row0 + quad * 4 + r;
            if (row < N_NODES) {
                float v = acc[t][r] + bj;
                Hh[(size_t)row * HID + c] = (_Float16)(v > 0.f ? v : 0.f);
            }
        }
    }
}

__global__ __launch_bounds__(256) void k_xform2_mfma(
    const _Float16* __restrict__ H, const float* __restrict__ W,
    const int* __restrict__ ideg, _Float16* __restrict__ T) {
    __shared__ _Float16 Wt[128 * 136];
    for (int idx = threadIdx.x; idx < 8192; idx += 256) {
        int n = idx & 127, k = (idx >> 7) * 2;
        pack2(&Wt[n * 136 + k], W[k * HID + n], W[(k + 1) * HID + n]);
    }
    __syncthreads();

    const int lane = threadIdx.x & 63;
    const int wave = threadIdx.x >> 6;
    const int m16 = lane & 15, quad = lane >> 4;
    const int row0 = blockIdx.x * 64 + wave * 16;
    if (row0 >= N_NODES) return;

    int arow = row0 + m16; if (arow >= N_NODES) arow = N_NODES - 1;
    const _Float16* hp = H + (size_t)arow * HID + quad * 8;
    half8 a[4];
#pragma unroll
    for (int kk = 0; kk < 4; ++kk) a[kk] = *(const half8*)(hp + kk * 32);

    floatx4 acc[8];
#pragma unroll
    for (int t = 0; t < 8; ++t) acc[t] = (floatx4){0.f, 0.f, 0.f, 0.f};
#pragma unroll
    for (int t = 0; t < 8; ++t) {
        const _Float16* wp = &Wt[(t * 16 + m16) * 136 + quad * 8];
#pragma unroll
        for (int kk = 0; kk < 4; ++kk) {
            half8 b = *(const half8*)(wp + kk * 32);
            acc[t] = __builtin_amdgcn_mfma_f32_16x16x32_f16(a[kk], b, acc[t], 0, 0, 0);
        }
    }
    float dis[4];
#pragma unroll
    for (int r = 0; r < 4; ++r) {
        int row = row0 + quad * 4 + r;
        dis[r] = (row < N_NODES) ? rsqrtf(1.0f + (float)ideg[row]) : 0.f;
    }
#pragma unroll
    for (int t = 0; t < 8; ++t) {
        int c = t * 16 + m16;
#pragma unroll
        for (int r = 0; r < 4; ++r) {
            int row = row0 + quad * 4 + r;
            if (row < N_NODES)
                T[(size_t)row * HID + c] = (_Float16)(acc[t][r] * dis[r]);
        }
    }
}

__global__ __launch_bounds__(256) void k_xform3_mfma(
    const _Float16* __restrict__ H, const float* __restrict__ W,
    const int* __restrict__ ideg, _Float16* __restrict__ T) {
    __shared__ _Float16 Wt[32 * 136];
    for (int idx = threadIdx.x; idx < 2048; idx += 256) {
        int n = idx & 31, k = (idx >> 5) * 2;
        pack2(&Wt[n * 136 + k], W[k * IN_F + n], W[(k + 1) * IN_F + n]);
    }
    __syncthreads();

    const int lane = threadIdx.x & 63;
    const int wave = threadIdx.x >> 6;
    const int m16 = lane & 15, quad = lane >> 4;
    const int row0 = blockIdx.x * 64 + wave * 16;
    if (row0 >= N_NODES) return;

    int arow = row0 + m16; if (arow >= N_NODES) arow = N_NODES - 1;
    const _Float16* hp = H + (size_t)arow * HID + quad * 8;
    half8 a[4];
#pragma unroll
    for (int kk = 0; kk < 4; ++kk) a[kk] = *(const half8*)(hp + kk * 32);

    floatx4 acc[2];
#pragma unroll
    for (int t = 0; t < 2; ++t) acc[t] = (floatx4){0.f, 0.f, 0.f, 0.f};
#pragma unroll
    for (int t = 0; t < 2; ++t) {
        const _Float16* wp = &Wt[(t * 16 + m16) * 136 + quad * 8];
#pragma unroll
        for (int kk = 0; kk < 4; ++kk) {
            half8 b = *(const half8*)(wp + kk * 32);
            acc[t] = __builtin_amdgcn_mfma_f32_16x16x32_f16(a[kk], b, acc[t], 0, 0, 0);
        }
    }
    float dis[4];
#pragma unroll
    for (int r = 0; r < 4; ++r) {
        int row = row0 + quad * 4 + r;
        dis[r] = (row < N_NODES) ? rsqrtf(1.0f + (float)ideg[row]) : 0.f;
    }
#pragma unroll
    for (int t = 0; t < 2; ++t) {
        int c = t * 16 + m16;
#pragma unroll
        for (int r = 0; r < 4; ++r) {
            int row = row0 + quad * 4 + r;
            if (row < N_NODES)
                T[(size_t)row * IN_F + c] = (_Float16)(acc[t][r] * dis[r]);
        }
    }
}

// ---------------- launch ----------------

extern "C" void kernel_launch(void* const* d_in, const int* in_sizes, int n_in,
                              void* d_out, int out_size, void* d_ws, size_t ws_size,
                              hipStream_t stream) {
    const float* x  = (const float*)d_in[0];
    const int*   ei = (const int*)d_in[1];
    const float* W1 = (const float*)d_in[2];
    const float* b1 = (const float*)d_in[3];
    const float* W2 = (const float*)d_in[4];
    const float* b2 = (const float*)d_in[5];
    const float* W3 = (const float*)d_in[6];
    const float* b3 = (const float*)d_in[7];
    float* out = (float*)d_out;

    const int* src = ei;             // edge_index[0]
    const int* dst = ei + N_EDGES;   // edge_index[1]

    // workspace layout
    int*      ideg  = (int*)d_ws;                          // 102400
    unsigned* seg   = (unsigned*)(ideg + 102400);          // 102400*NSH
    int*      bcnt  = (int*)(seg + 102400 * NSH);          // 256
    int*      bbase = bcnt + 256;                          // 256 (197 used)
    int*      bcur  = bbase + 256;                         // 256
    int*      barA  = bcur + 256;                          // 128 (g32pre)
    int*      barB  = barA + 128;                          // 128 (g128)
    int*      barC  = barB + 128;                          // 128 (g32fin)
    int*      col   = barC + 128;                          // E
    unsigned* rec   = (unsigned*)(col + N_EDGES);          // E (dead after fill3)
    _Float16* t1h   = (_Float16*)rec;                      // ALIASES rec: N*32 fp16
    _Float16* z     = (_Float16*)(rec + N_EDGES);          // N*32 fp16
    _Float16* H1h   = z + (size_t)N_NODES * IN_F;          // N*128 fp16
    _Float16* T2h   = H1h + (size_t)N_NODES * HID;         // N*128 fp16 (reused as T3)
    _Float16* H2h   = T2h + (size_t)N_NODES * HID;         // N*128 fp16

    const int xgrid = (N_NODES + 63) / 64;   // 1563

    // zero bcnt + barrier counters (contiguous region)
    hipMemsetAsync(bcnt, 0, (256 * 3 + 128 * 3) * sizeof(int), stream);

    // ---- CSR build (bucketed; shard-major col + packed seg) ----
    k_bcount<<<NBB, 256, 0, stream>>>(dst, bcnt);
    k_bscan<<<1, 256, 0, stream>>>(bcnt, bbase, bcur);
    k_bucket<<<NBB, 256, 0, stream>>>(src, dst, bcur, rec);
    k_fill3<<<NBUCK, 256, 0, stream>>>(rec, bbase, ideg, seg, col);

    // ---- layer 1 (aggregate-first; sharded 32-dim gather, then MFMA 32->128) ----
    k_prescale<<<(N_NODES * 16 + 255) / 256, 256, 0, stream>>>(
        (const float2*)x, ideg, (__half2*)t1h);
    k_gather32p_sh<<<GGRID, 256, 0, stream>>>(seg, ideg, col, t1h, z, barA);
    k_xform1_mfma<<<xgrid, 256, 0, stream>>>(z, W1, b1, H1h);

    // ---- layer 2 (MFMA 128->128, then sharded 128-dim gather) ----
    k_xform2_mfma<<<xgrid, 256, 0, stream>>>(H1h, W2, ideg, T2h);
    k_gather128_sh<<<GGRID, 256, 0, stream>>>(seg, ideg, col, T2h, b2, H2h, barB);

    // ---- layer 3 (MFMA 128->32, then sharded 32-dim gather) ----
    k_xform3_mfma<<<xgrid, 256, 0, stream>>>(H2h, W3, ideg, T2h);
    k_gather32f_sh<<<GGRID, 256, 0, stream>>>(seg, ideg, col, T2h, b3, out, barC);
}

// Round 4
// 2199.216 us; speedup vs baseline: 1.3021x; 1.3021x over previous
//
#include <hip/hip_runtime.h>
#include <hip/hip_fp16.h>

#define N_NODES 100000
#define N_EDGES 1600000
#define IN_F 32
#define HID 128
#define BSHIFT 9
#define BSIZE 512
#define NBUCK 196       // ceil(100000/512)
#define EPB 8192        // edges per bucket-phase block
#define NBB 196         // ceil(E/EPB)
#define COLSZ 3206144   // padded CSR capacity: E + 8192*195 + 7695, rounded up
#define CHUNK 2         // work-steal granularity (nodes per atomic grab)

typedef _Float16 half8 __attribute__((ext_vector_type(8)));
typedef float floatx4 __attribute__((ext_vector_type(4)));

static __device__ __forceinline__ void pack2(_Float16* dst, float a, float b) {
    union { _Float16 h[2]; unsigned u; } p;
    p.h[0] = (_Float16)a; p.h[1] = (_Float16)b;
    *(unsigned*)dst = p.u;
}

// ---------------- CSR build (bucketed, no global per-node atomics) ----------------

__global__ __launch_bounds__(256) void k_bcount(const int* __restrict__ dst,
                                                int* __restrict__ bcnt) {
    __shared__ int hist[256];
    hist[threadIdx.x] = 0;
    __syncthreads();
    const int e0 = blockIdx.x * EPB;
#pragma unroll 4
    for (int k = 0; k < 32; ++k) {
        int e = e0 + k * 256 + threadIdx.x;
        if (e < N_EDGES) atomicAdd(&hist[dst[e] >> BSHIFT], 1);
    }
    __syncthreads();
    int c = hist[threadIdx.x];
    if (c > 0) atomicAdd(&bcnt[threadIdx.x], c);
}

__global__ __launch_bounds__(256) void k_bscan(const int* __restrict__ bcnt,
                                               int* __restrict__ bbase,
                                               int* __restrict__ bcur) {
    __shared__ int s[256];
    int v = (threadIdx.x < NBUCK) ? bcnt[threadIdx.x] : 0;
    s[threadIdx.x] = v;
    __syncthreads();
    for (int off = 1; off < 256; off <<= 1) {
        int t = (threadIdx.x >= off) ? s[threadIdx.x - off] : 0;
        __syncthreads();
        s[threadIdx.x] += t;
        __syncthreads();
    }
    if (threadIdx.x < NBUCK) {
        int ex = s[threadIdx.x] - v;
        bbase[threadIdx.x] = ex;
        bcur[threadIdx.x]  = ex;
    }
    if (threadIdx.x == 0) bbase[NBUCK] = N_EDGES;
}

__global__ __launch_bounds__(256) void k_bucket(const int* __restrict__ src,
                                                const int* __restrict__ dst,
                                                int* __restrict__ bcur,
                                                unsigned* __restrict__ rec) {
    __shared__ int hist[256];
    __shared__ int lbase[256];
    const int e0 = blockIdx.x * EPB;
    hist[threadIdx.x] = 0;
    __syncthreads();

    unsigned rk[32]; short bk[32];
#pragma unroll
    for (int k = 0; k < 32; ++k) {
        int e = e0 + k * 256 + threadIdx.x;
        if (e < N_EDGES) {
            int d = dst[e];
            int b = d >> BSHIFT;
            bk[k] = (short)b;
            rk[k] = ((unsigned)src[e] << BSHIFT) | (unsigned)(d & (BSIZE - 1));
            atomicAdd(&hist[b], 1);
        } else bk[k] = -1;
    }
    __syncthreads();
    int c = hist[threadIdx.x];
    lbase[threadIdx.x] = (c > 0) ? atomicAdd(&bcur[threadIdx.x], c) : 0;
    __syncthreads();
    hist[threadIdx.x] = 0;   // reuse as local running offset
    __syncthreads();
#pragma unroll
    for (int k = 0; k < 32; ++k) {
        if (bk[k] >= 0) {
            int off = atomicAdd(&hist[bk[k]], 1);
            rec[lbase[bk[k]] + off] = rk[k];
        }
    }
}

// per bucket: LDS degree count + PADDED scan (rows padded to multiple of 16,
// pad slots -> node N_NODES = zero row). cursor[n] is 16-aligned so gathers can
// run branch-free with int4 col loads.
__global__ __launch_bounds__(256) void k_fill3(const unsigned* __restrict__ rec,
                                               const int* __restrict__ bbase,
                                               int* __restrict__ ideg,
                                               int* __restrict__ cursor,
                                               int* __restrict__ col) {
    __shared__ int lcnt[BSIZE];
    __shared__ int lcur[BSIZE];
    __shared__ int lend[BSIZE];
    __shared__ int s[256];
    const int b = blockIdx.x;
    const int n0 = b << BSHIFT;
    const int rbeg = bbase[b];
    const int rend = bbase[b + 1];
    // padded bucket base: static +8192/bucket covers worst pad (15*512=7680)
    const int pbeg = ((rbeg + 15) & ~15) + (16 * BSIZE) * b;

    lcnt[threadIdx.x] = 0;
    lcnt[threadIdx.x + 256] = 0;
    __syncthreads();
    for (int i = rbeg + threadIdx.x; i < rend; i += 256)
        atomicAdd(&lcnt[rec[i] & (BSIZE - 1)], 1);
    __syncthreads();

    int a0 = lcnt[2 * threadIdx.x], a1 = lcnt[2 * threadIdx.x + 1];
    int p0 = (a0 + 15) & ~15, p1 = (a1 + 15) & ~15;
    int pv = p0 + p1;
    s[threadIdx.x] = pv;
    __syncthreads();
    for (int off = 1; off < 256; off <<= 1) {
        int t = (threadIdx.x >= off) ? s[threadIdx.x - off] : 0;
        __syncthreads();
        s[threadIdx.x] += t;
        __syncthreads();
    }
    int ex = s[threadIdx.x] - pv;            // exclusive over padded pairs
    int c0 = pbeg + ex;
    int c1 = c0 + p0;
    lcur[2 * threadIdx.x]     = c0;  lend[2 * threadIdx.x]     = c0 + p0;
    lcur[2 * threadIdx.x + 1] = c1;  lend[2 * threadIdx.x + 1] = c1 + p1;
    __syncthreads();

    for (int t = threadIdx.x; t < BSIZE; t += 256) {
        int n = n0 + t;
        if (n < N_NODES) {
            ideg[n]   = lcnt[t];
            cursor[n] = lcur[t];
        }
    }
    __syncthreads();
    for (int i = rbeg + threadIdx.x; i < rend; i += 256) {
        unsigned r = rec[i];
        int slot = atomicAdd(&lcur[r & (BSIZE - 1)], 1);
        col[slot] = (int)(r >> BSHIFT);
    }
    __syncthreads();
    // fill pad slots with the zero-row index
    for (int t = threadIdx.x; t < BSIZE; t += 256) {
        int e2 = lend[t];
        for (int k = lcur[t]; k < e2; ++k) col[k] = N_NODES;
    }
}

// ---------------- layer-1 prescale: t1 = x * dis (fp16, 32-dim) ----------------

__global__ void k_prescale(const float2* __restrict__ x, const int* __restrict__ ideg,
                           __half2* __restrict__ T) {
    // zero row at index N_NODES for pad gathers
    if (blockIdx.x == 0 && threadIdx.x < 16)
        ((unsigned*)(T + (size_t)N_NODES * 16))[threadIdx.x] = 0u;
    int tid = blockIdx.x * 256 + threadIdx.x;
    if (tid >= N_NODES * 16) return;
    int i = tid >> 4;
    float dis = rsqrtf(1.0f + (float)ideg[i]);
    float2 v = x[tid];
    T[tid] = __floats2half2_rn(v.x * dis, v.y * dis);
}

// ---------------- gathers (branch-free padded CSR, work-stealing) ----------------

static __device__ __forceinline__ int steal(int* ctr, int lane) {
    int base;
    if (lane == 0) base = atomicAdd(ctr, CHUNK);
    return __shfl(base, 0, 64);
}

// pre: z = acc*dis, fp16 out. 16 slots x 4 feat-lanes, x2-deep pipeline.
__global__ __launch_bounds__(256) void k_gather32_pre(
    const int* __restrict__ cursor, const int* __restrict__ ideg,
    const int* __restrict__ col, const _Float16* __restrict__ T,
    _Float16* __restrict__ OUT, int* __restrict__ gctr) {
    const int lane = threadIdx.x & 63;
    const int slot = lane >> 2;
    const int fl   = lane & 3;

    for (;;) {
        int base = steal(gctr, lane);
        if (base >= N_NODES) break;
        int nlim = base + CHUNK < N_NODES ? base + CHUNK : N_NODES;
        for (int node = base; node < nlim; ++node) {
            int begin = cursor[node];
            int d     = ideg[node];
            int nb    = (d + 15) >> 4;
            float acc[8];
            if (slot == 0) {
                half8 v = *(const half8*)(T + (size_t)node * IN_F + fl * 8);
#pragma unroll
                for (int i = 0; i < 8; ++i) acc[i] = (float)v[i];
            } else {
#pragma unroll
                for (int i = 0; i < 8; ++i) acc[i] = 0.f;
            }
            const int* cp = col + begin + slot;
            int itb = 0;
            for (; itb + 2 <= nb; itb += 2, cp += 32) {
                int s0 = cp[0];
                int s1 = cp[16];
                half8 v0 = *(const half8*)(T + (size_t)s0 * IN_F + fl * 8);
                half8 v1 = *(const half8*)(T + (size_t)s1 * IN_F + fl * 8);
#pragma unroll
                for (int i = 0; i < 8; ++i) acc[i] += (float)v0[i] + (float)v1[i];
            }
            if (itb < nb) {
                int s0 = cp[0];
                half8 v0 = *(const half8*)(T + (size_t)s0 * IN_F + fl * 8);
#pragma unroll
                for (int i = 0; i < 8; ++i) acc[i] += (float)v0[i];
            }
#pragma unroll
            for (int m = 4; m < 64; m <<= 1)
#pragma unroll
                for (int i = 0; i < 8; ++i) acc[i] += __shfl_xor(acc[i], m, 64);
            if (slot == 0) {
                float dis = rsqrtf(1.0f + (float)d);
                half8 o;
#pragma unroll
                for (int i = 0; i < 8; ++i) o[i] = (_Float16)(acc[i] * dis);
                *(half8*)(OUT + (size_t)node * IN_F + fl * 8) = o;
            }
        }
    }
}

// fin: out = relu(acc*dis + b), fp32 out
__global__ __launch_bounds__(256) void k_gather32_fin(
    const int* __restrict__ cursor, const int* __restrict__ ideg,
    const int* __restrict__ col, const _Float16* __restrict__ T,
    const float* __restrict__ b, float* __restrict__ OUT,
    int* __restrict__ gctr) {
    const int lane = threadIdx.x & 63;
    const int slot = lane >> 2;
    const int fl   = lane & 3;

    float4 bb0 = *(const float4*)(b + fl * 8);
    float4 bb1 = *(const float4*)(b + fl * 8 + 4);
    float bias[8] = {bb0.x, bb0.y, bb0.z, bb0.w, bb1.x, bb1.y, bb1.z, bb1.w};

    for (;;) {
        int base = steal(gctr, lane);
        if (base >= N_NODES) break;
        int nlim = base + CHUNK < N_NODES ? base + CHUNK : N_NODES;
        for (int node = base; node < nlim; ++node) {
            int begin = cursor[node];
            int d     = ideg[node];
            int nb    = (d + 15) >> 4;
            float acc[8];
            if (slot == 0) {
                half8 v = *(const half8*)(T + (size_t)node * IN_F + fl * 8);
#pragma unroll
                for (int i = 0; i < 8; ++i) acc[i] = (float)v[i];
            } else {
#pragma unroll
                for (int i = 0; i < 8; ++i) acc[i] = 0.f;
            }
            const int* cp = col + begin + slot;
            int itb = 0;
            for (; itb + 2 <= nb; itb += 2, cp += 32) {
                int s0 = cp[0];
                int s1 = cp[16];
                half8 v0 = *(const half8*)(T + (size_t)s0 * IN_F + fl * 8);
                half8 v1 = *(const half8*)(T + (size_t)s1 * IN_F + fl * 8);
#pragma unroll
                for (int i = 0; i < 8; ++i) acc[i] += (float)v0[i] + (float)v1[i];
            }
            if (itb < nb) {
                int s0 = cp[0];
                half8 v0 = *(const half8*)(T + (size_t)s0 * IN_F + fl * 8);
#pragma unroll
                for (int i = 0; i < 8; ++i) acc[i] += (float)v0[i];
            }
#pragma unroll
            for (int m = 4; m < 64; m <<= 1)
#pragma unroll
                for (int i = 0; i < 8; ++i) acc[i] += __shfl_xor(acc[i], m, 64);
            if (slot == 0) {
                float dis = rsqrtf(1.0f + (float)d);
                float o[8];
#pragma unroll
                for (int i = 0; i < 8; ++i) {
                    float v = acc[i] * dis + bias[i];
                    o[i] = v > 0.f ? v : 0.f;
                }
                float* op = OUT + (size_t)node * IN_F + fl * 8;
                *(float4*)op       = make_float4(o[0], o[1], o[2], o[3]);
                *(float4*)(op + 4) = make_float4(o[4], o[5], o[6], o[7]);
            }
        }
    }
}

// 128-dim: 4 slots x 16 feat-lanes. Padded rows -> one int4 col load + 4
// independent 256B row loads in flight per step, no bounds checks.
__global__ __launch_bounds__(256) void k_gather128(
    const int* __restrict__ cursor, const int* __restrict__ ideg,
    const int* __restrict__ col, const _Float16* __restrict__ T,
    const float* __restrict__ b, _Float16* __restrict__ OUT,
    int* __restrict__ gctr) {
    const int lane = threadIdx.x & 63;
    const int slot = lane >> 4;
    const int fl   = lane & 15;

    float4 bb0 = *(const float4*)(b + fl * 8);
    float4 bb1 = *(const float4*)(b + fl * 8 + 4);
    float bias[8] = {bb0.x, bb0.y, bb0.z, bb0.w, bb1.x, bb1.y, bb1.z, bb1.w};

    for (;;) {
        int base = steal(gctr, lane);
        if (base >= N_NODES) break;
        int nlim = base + CHUNK < N_NODES ? base + CHUNK : N_NODES;
        for (int node = base; node < nlim; ++node) {
            int begin = cursor[node];
            int d     = ideg[node];
            int nb    = (d + 15) >> 4;
            float acc[8];
            if (slot == 0) {
                half8 v = *(const half8*)(T + (size_t)node * HID + fl * 8);
#pragma unroll
                for (int i = 0; i < 8; ++i) acc[i] = (float)v[i];
            } else {
#pragma unroll
                for (int i = 0; i < 8; ++i) acc[i] = 0.f;
            }
            const int* cp = col + begin + slot * 4;   // 16B-aligned (cursor % 16 == 0)
            for (int itb = 0; itb < nb; ++itb, cp += 16) {
                int4 cc = *(const int4*)cp;
                half8 v0 = *(const half8*)(T + (size_t)cc.x * HID + fl * 8);
                half8 v1 = *(const half8*)(T + (size_t)cc.y * HID + fl * 8);
                half8 v2 = *(const half8*)(T + (size_t)cc.z * HID + fl * 8);
                half8 v3 = *(const half8*)(T + (size_t)cc.w * HID + fl * 8);
#pragma unroll
                for (int i = 0; i < 8; ++i)
                    acc[i] += ((float)v0[i] + (float)v1[i]) + ((float)v2[i] + (float)v3[i]);
            }
#pragma unroll
            for (int m = 16; m < 64; m <<= 1)
#pragma unroll
                for (int i = 0; i < 8; ++i) acc[i] += __shfl_xor(acc[i], m, 64);
            if (slot == 0) {
                float dis = rsqrtf(1.0f + (float)d);
                half8 o;
#pragma unroll
                for (int i = 0; i < 8; ++i) {
                    float v = acc[i] * dis + bias[i];
                    o[i] = (_Float16)(v > 0.f ? v : 0.f);
                }
                *(half8*)(OUT + (size_t)node * HID + fl * 8) = o;
            }
        }
    }
}

// ---------------- MFMA transforms (r9-proven) ----------------
// 16x16x32 layouts: A[m=lane&15][k=quad*8+j], B[k=quad*8+j][n=lane&15],
// D[row=quad*4+r][col=lane&15]. Block = 4 waves x 16 rows = 64 rows.

__global__ __launch_bounds__(256) void k_xform1_mfma(
    const _Float16* __restrict__ z, const float* __restrict__ W,
    const float* __restrict__ bias, _Float16* __restrict__ Hh) {
    __shared__ _Float16 Wt[128 * 40];
    for (int idx = threadIdx.x; idx < 2048; idx += 256) {
        int n = idx & 127, k = (idx >> 7) * 2;
        pack2(&Wt[n * 40 + k], W[k * HID + n], W[(k + 1) * HID + n]);
    }
    __syncthreads();

    const int lane = threadIdx.x & 63;
    const int wave = threadIdx.x >> 6;
    const int m16 = lane & 15, quad = lane >> 4;
    const int row0 = blockIdx.x * 64 + wave * 16;
    if (row0 >= N_NODES) return;

    int arow = row0 + m16; if (arow >= N_NODES) arow = N_NODES - 1;
    half8 a = *(const half8*)(z + (size_t)arow * IN_F + quad * 8);

    floatx4 acc[8];
#pragma unroll
    for (int t = 0; t < 8; ++t) acc[t] = (floatx4){0.f, 0.f, 0.f, 0.f};
#pragma unroll
    for (int t = 0; t < 8; ++t) {
        half8 b = *(const half8*)&Wt[(t * 16 + m16) * 40 + quad * 8];
        acc[t] = __builtin_amdgcn_mfma_f32_16x16x32_f16(a, b, acc[t], 0, 0, 0);
    }
#pragma unroll
    for (int t = 0; t < 8; ++t) {
        int c = t * 16 + m16;
        float bj = bias[c];
#pragma unroll
        for (int r = 0; r < 4; ++r) {
            int row = row0 + quad * 4 + r;
            if (row < N_NODES) {
                float v = acc[t][r] + bj;
                Hh[(size_t)row * HID + c] = (_Float16)(v > 0.f ? v : 0.f);
            }
        }
    }
}

__global__ __launch_bounds__(256) void k_xform2_mfma(
    const _Float16* __restrict__ H, const float* __restrict__ W,
    const int* __restrict__ ideg, _Float16* __restrict__ T) {
    // zero row at index N_NODES (128-dim view) for pad gathers in k_gather128
    if (blockIdx.x == 0 && threadIdx.x < 64)
        ((unsigned*)(T + (size_t)N_NODES * HID))[threadIdx.x] = 0u;
    __shared__ _Float16 Wt[128 * 136];
    for (int idx = threadIdx.x; idx < 8192; idx += 256) {
        int n = idx & 127, k = (idx >> 7) * 2;
        pack2(&Wt[n * 136 + k], W[k * HID + n], W[(k + 1) * HID + n]);
    }
    __syncthreads();

    const int lane = threadIdx.x & 63;
    const int wave = threadIdx.x >> 6;
    const int m16 = lane & 15, quad = lane >> 4;
    const int row0 = blockIdx.x * 64 + wave * 16;
    if (row0 >= N_NODES) return;

    int arow = row0 + m16; if (arow >= N_NODES) arow = N_NODES - 1;
    const _Float16* hp = H + (size_t)arow * HID + quad * 8;
    half8 a[4];
#pragma unroll
    for (int kk = 0; kk < 4; ++kk) a[kk] = *(const half8*)(hp + kk * 32);

    floatx4 acc[8];
#pragma unroll
    for (int t = 0; t < 8; ++t) acc[t] = (floatx4){0.f, 0.f, 0.f, 0.f};
#pragma unroll
    for (int t = 0; t < 8; ++t) {
        const _Float16* wp = &Wt[(t * 16 + m16) * 136 + quad * 8];
#pragma unroll
        for (int kk = 0; kk < 4; ++kk) {
            half8 b = *(const half8*)(wp + kk * 32);
            acc[t] = __builtin_amdgcn_mfma_f32_16x16x32_f16(a[kk], b, acc[t], 0, 0, 0);
        }
    }
    float dis[4];
#pragma unroll
    for (int r = 0; r < 4; ++r) {
        int row = row0 + quad * 4 + r;
        dis[r] = (row < N_NODES) ? rsqrtf(1.0f + (float)ideg[row]) : 0.f;
    }
#pragma unroll
    for (int t = 0; t < 8; ++t) {
        int c = t * 16 + m16;
#pragma unroll
        for (int r = 0; r < 4; ++r) {
            int row = row0 + quad * 4 + r;
            if (row < N_NODES)
                T[(size_t)row * HID + c] = (_Float16)(acc[t][r] * dis[r]);
        }
    }
}

__global__ __launch_bounds__(256) void k_xform3_mfma(
    const _Float16* __restrict__ H, const float* __restrict__ W,
    const int* __restrict__ ideg, _Float16* __restrict__ T) {
    // zero row at index N_NODES (32-dim view) for pad gathers in k_gather32_fin
    if (blockIdx.x == 0 && threadIdx.x < 16)
        ((unsigned*)(T + (size_t)N_NODES * IN_F))[threadIdx.x] = 0u;
    __shared__ _Float16 Wt[32 * 136];
    for (int idx = threadIdx.x; idx < 2048; idx += 256) {
        int n = idx & 31, k = (idx >> 5) * 2;
        pack2(&Wt[n * 136 + k], W[k * IN_F + n], W[(k + 1) * IN_F + n]);
    }
    __syncthreads();

    const int lane = threadIdx.x & 63;
    const int wave = threadIdx.x >> 6;
    const int m16 = lane & 15, quad = lane >> 4;
    const int row0 = blockIdx.x * 64 + wave * 16;
    if (row0 >= N_NODES) return;

    int arow = row0 + m16; if (arow >= N_NODES) arow = N_NODES - 1;
    const _Float16* hp = H + (size_t)arow * HID + quad * 8;
    half8 a[4];
#pragma unroll
    for (int kk = 0; kk < 4; ++kk) a[kk] = *(const half8*)(hp + kk * 32);

    floatx4 acc[2];
#pragma unroll
    for (int t = 0; t < 2; ++t) acc[t] = (floatx4){0.f, 0.f, 0.f, 0.f};
#pragma unroll
    for (int t = 0; t < 2; ++t) {
        const _Float16* wp = &Wt[(t * 16 + m16) * 136 + quad * 8];
#pragma unroll
        for (int kk = 0; kk < 4; ++kk) {
            half8 b = *(const half8*)(wp + kk * 32);
            acc[t] = __builtin_amdgcn_mfma_f32_16x16x32_f16(a[kk], b, acc[t], 0, 0, 0);
        }
    }
    float dis[4];
#pragma unroll
    for (int r = 0; r < 4; ++r) {
        int row = row0 + quad * 4 + r;
        dis[r] = (row < N_NODES) ? rsqrtf(1.0f + (float)ideg[row]) : 0.f;
    }
#pragma unroll
    for (int t = 0; t < 2; ++t) {
        int c = t * 16 + m16;
#pragma unroll
        for (int r = 0; r < 4; ++r) {
            int row = row0 + quad * 4 + r;
            if (row < N_NODES)
                T[(size_t)row * IN_F + c] = (_Float16)(acc[t][r] * dis[r]);
        }
    }
}

// ---------------- launch ----------------

extern "C" void kernel_launch(void* const* d_in, const int* in_sizes, int n_in,
                              void* d_out, int out_size, void* d_ws, size_t ws_size,
                              hipStream_t stream) {
    const float* x  = (const float*)d_in[0];
    const int*   ei = (const int*)d_in[1];
    const float* W1 = (const float*)d_in[2];
    const float* b1 = (const float*)d_in[3];
    const float* W2 = (const float*)d_in[4];
    const float* b2 = (const float*)d_in[5];
    const float* W3 = (const float*)d_in[6];
    const float* b3 = (const float*)d_in[7];
    float* out = (float*)d_out;

    const int* src = ei;             // edge_index[0]
    const int* dst = ei + N_EDGES;   // edge_index[1]

    // workspace layout (all offsets 16B-aligned)
    int*      ideg   = (int*)d_ws;                           // N (padded 102400)
    int*      cursor = ideg + 102400;                        // N
    int*      bcnt   = cursor + 102400;                      // 256
    int*      bbase  = bcnt + 256;                           // 256 (197 used)
    int*      bcur   = bbase + 256;                          // 256
    int*      gctr   = bcur + 256;                           // 256 (3 used, 128B apart)
    int*      col    = gctr + 256;                           // COLSZ (padded CSR)
    unsigned* rec    = (unsigned*)(col + COLSZ);             // E (dead after k_fill3)
    _Float16* t1h    = (_Float16*)rec;                       // ALIASES rec: (N+pad)*32 fp16
    _Float16* z      = t1h + (size_t)N_NODES * IN_F + 64;    // N*32 fp16
    _Float16* H1h    = z + (size_t)N_NODES * IN_F;           // N*128 fp16
    _Float16* T2h    = H1h + (size_t)N_NODES * HID;          // (N+1)*128 fp16 (reused as T3)
    _Float16* H2h    = T2h + (size_t)N_NODES * HID + 128;    // N*128 fp16

    const int xgrid = (N_NODES + 63) / 64;   // 1563

    // zero bcnt + steal counters (bbase/bcur overwritten by bscan anyway)
    hipMemsetAsync(bcnt, 0, 4 * 256 * sizeof(int), stream);

    // ---- CSR build (bucketed; no global per-node atomics) ----
    k_bcount<<<NBB, 256, 0, stream>>>(dst, bcnt);
    k_bscan<<<1, 256, 0, stream>>>(bcnt, bbase, bcur);
    k_bucket<<<NBB, 256, 0, stream>>>(src, dst, bcur, rec);
    k_fill3<<<NBUCK, 256, 0, stream>>>(rec, bbase, ideg, cursor, col);

    // ---- layer 1 (aggregate-first; 32-dim gather, then MFMA 32->128) ----
    k_prescale<<<(N_NODES * 16 + 255) / 256, 256, 0, stream>>>(
        (const float2*)x, ideg, (__half2*)t1h);
    k_gather32_pre<<<2048, 256, 0, stream>>>(cursor, ideg, col, t1h, z, gctr);
    k_xform1_mfma<<<xgrid, 256, 0, stream>>>(z, W1, b1, H1h);

    // ---- layer 2 (MFMA 128->128, then 128-dim fp16 gather) ----
    k_xform2_mfma<<<xgrid, 256, 0, stream>>>(H1h, W2, ideg, T2h);
    k_gather128<<<2048, 256, 0, stream>>>(cursor, ideg, col, T2h, b2, H2h, gctr + 32);

    // ---- layer 3 (MFMA 128->32, then 32-dim fp16 gather) ----
    k_xform3_mfma<<<xgrid, 256, 0, stream>>>(H2h, W3, ideg, T2h);
    k_gather32_fin<<<2048, 256, 0, stream>>>(cursor, ideg, col, T2h, b3, out, gctr + 64);
}

// Round 5
// 329.125 us; speedup vs baseline: 8.7004x; 6.6820x over previous
//
#include <hip/hip_runtime.h>
#include <hip/hip_fp16.h>

#define N_NODES 100000
#define N_EDGES 1600000
#define IN_F 32
#define HID 128
#define BSHIFT 9
#define BSIZE 512
#define NBUCK 196       // ceil(100000/512)
#define EPB 8192        // edges per bucket-phase block
#define NBB 196         // ceil(E/EPB)
#define COLSZ 3206144   // padded CSR capacity: E + 8192*195 + 7695, rounded up

typedef _Float16 half8 __attribute__((ext_vector_type(8)));
typedef float floatx4 __attribute__((ext_vector_type(4)));

static __device__ __forceinline__ void pack2(_Float16* dst, float a, float b) {
    union { _Float16 h[2]; unsigned u; } p;
    p.h[0] = (_Float16)a; p.h[1] = (_Float16)b;
    *(unsigned*)dst = p.u;
}

// ---------------- CSR build (bucketed, no global per-node atomics) ----------------

__global__ __launch_bounds__(256) void k_bcount(const int* __restrict__ dst,
                                                int* __restrict__ bcnt) {
    __shared__ int hist[256];
    hist[threadIdx.x] = 0;
    __syncthreads();
    const int e0 = blockIdx.x * EPB;
#pragma unroll 4
    for (int k = 0; k < 32; ++k) {
        int e = e0 + k * 256 + threadIdx.x;
        if (e < N_EDGES) atomicAdd(&hist[dst[e] >> BSHIFT], 1);
    }
    __syncthreads();
    int c = hist[threadIdx.x];
    if (c > 0) atomicAdd(&bcnt[threadIdx.x], c);
}

__global__ __launch_bounds__(256) void k_bscan(const int* __restrict__ bcnt,
                                               int* __restrict__ bbase,
                                               int* __restrict__ bcur) {
    __shared__ int s[256];
    int v = (threadIdx.x < NBUCK) ? bcnt[threadIdx.x] : 0;
    s[threadIdx.x] = v;
    __syncthreads();
    for (int off = 1; off < 256; off <<= 1) {
        int t = (threadIdx.x >= off) ? s[threadIdx.x - off] : 0;
        __syncthreads();
        s[threadIdx.x] += t;
        __syncthreads();
    }
    if (threadIdx.x < NBUCK) {
        int ex = s[threadIdx.x] - v;
        bbase[threadIdx.x] = ex;
        bcur[threadIdx.x]  = ex;
    }
    if (threadIdx.x == 0) bbase[NBUCK] = N_EDGES;
}

__global__ __launch_bounds__(256) void k_bucket(const int* __restrict__ src,
                                                const int* __restrict__ dst,
                                                int* __restrict__ bcur,
                                                unsigned* __restrict__ rec) {
    __shared__ int hist[256];
    __shared__ int lbase[256];
    const int e0 = blockIdx.x * EPB;
    hist[threadIdx.x] = 0;
    __syncthreads();

    unsigned rk[32]; short bk[32];
#pragma unroll
    for (int k = 0; k < 32; ++k) {
        int e = e0 + k * 256 + threadIdx.x;
        if (e < N_EDGES) {
            int d = dst[e];
            int b = d >> BSHIFT;
            bk[k] = (short)b;
            rk[k] = ((unsigned)src[e] << BSHIFT) | (unsigned)(d & (BSIZE - 1));
            atomicAdd(&hist[b], 1);
        } else bk[k] = -1;
    }
    __syncthreads();
    int c = hist[threadIdx.x];
    lbase[threadIdx.x] = (c > 0) ? atomicAdd(&bcur[threadIdx.x], c) : 0;
    __syncthreads();
    hist[threadIdx.x] = 0;   // reuse as local running offset
    __syncthreads();
#pragma unroll
    for (int k = 0; k < 32; ++k) {
        if (bk[k] >= 0) {
            int off = atomicAdd(&hist[bk[k]], 1);
            rec[lbase[bk[k]] + off] = rk[k];
        }
    }
}

// per bucket: LDS degree count + PADDED scan (rows padded to multiple of 16,
// pad slots -> node N_NODES = zero row). cursor[n] is 16-aligned so gathers can
// run branch-free with int4 col loads.
__global__ __launch_bounds__(256) void k_fill3(const unsigned* __restrict__ rec,
                                               const int* __restrict__ bbase,
                                               int* __restrict__ ideg,
                                               int* __restrict__ cursor,
                                               int* __restrict__ col) {
    __shared__ int lcnt[BSIZE];
    __shared__ int lcur[BSIZE];
    __shared__ int lend[BSIZE];
    __shared__ int s[256];
    const int b = blockIdx.x;
    const int n0 = b << BSHIFT;
    const int rbeg = bbase[b];
    const int rend = bbase[b + 1];
    // padded bucket base: static +8192/bucket covers worst pad (15*512=7680)
    const int pbeg = ((rbeg + 15) & ~15) + (16 * BSIZE) * b;

    lcnt[threadIdx.x] = 0;
    lcnt[threadIdx.x + 256] = 0;
    __syncthreads();
    for (int i = rbeg + threadIdx.x; i < rend; i += 256)
        atomicAdd(&lcnt[rec[i] & (BSIZE - 1)], 1);
    __syncthreads();

    int a0 = lcnt[2 * threadIdx.x], a1 = lcnt[2 * threadIdx.x + 1];
    int p0 = (a0 + 15) & ~15, p1 = (a1 + 15) & ~15;
    int pv = p0 + p1;
    s[threadIdx.x] = pv;
    __syncthreads();
    for (int off = 1; off < 256; off <<= 1) {
        int t = (threadIdx.x >= off) ? s[threadIdx.x - off] : 0;
        __syncthreads();
        s[threadIdx.x] += t;
        __syncthreads();
    }
    int ex = s[threadIdx.x] - pv;            // exclusive over padded pairs
    int c0 = pbeg + ex;
    int c1 = c0 + p0;
    lcur[2 * threadIdx.x]     = c0;  lend[2 * threadIdx.x]     = c0 + p0;
    lcur[2 * threadIdx.x + 1] = c1;  lend[2 * threadIdx.x + 1] = c1 + p1;
    __syncthreads();

    for (int t = threadIdx.x; t < BSIZE; t += 256) {
        int n = n0 + t;
        if (n < N_NODES) {
            ideg[n]   = lcnt[t];
            cursor[n] = lcur[t];
        }
    }
    __syncthreads();
    for (int i = rbeg + threadIdx.x; i < rend; i += 256) {
        unsigned r = rec[i];
        int slot = atomicAdd(&lcur[r & (BSIZE - 1)], 1);
        col[slot] = (int)(r >> BSHIFT);
    }
    __syncthreads();
    // fill pad slots with the zero-row index
    for (int t = threadIdx.x; t < BSIZE; t += 256) {
        int e2 = lend[t];
        for (int k = lcur[t]; k < e2; ++k) col[k] = N_NODES;
    }
}

// ---------------- layer-1 prescale: t1 = x * dis (fp16, 32-dim) ----------------

__global__ void k_prescale(const float2* __restrict__ x, const int* __restrict__ ideg,
                           __half2* __restrict__ T) {
    // zero row at index N_NODES for pad gathers
    if (blockIdx.x == 0 && threadIdx.x < 16)
        ((unsigned*)(T + (size_t)N_NODES * 16))[threadIdx.x] = 0u;
    int tid = blockIdx.x * 256 + threadIdx.x;
    if (tid >= N_NODES * 16) return;
    int i = tid >> 4;
    float dis = rsqrtf(1.0f + (float)ideg[i]);
    float2 v = x[tid];
    T[tid] = __floats2half2_rn(v.x * dis, v.y * dis);
}

// ---------------- gathers (branch-free padded CSR, static partition) ----------------

// pre: z = acc*dis, fp16 out. 16 slots x 4 feat-lanes, x2-deep pipeline.
__global__ __launch_bounds__(256) void k_gather32_pre(
    const int* __restrict__ cursor, const int* __restrict__ ideg,
    const int* __restrict__ col, const _Float16* __restrict__ T,
    _Float16* __restrict__ OUT) {
    const int lane = threadIdx.x & 63;
    const int slot = lane >> 2;
    const int fl   = lane & 3;
    const int wid  = blockIdx.x * 4 + (threadIdx.x >> 6);
    const int wstride = gridDim.x * 4;

    for (int node = wid; node < N_NODES; node += wstride) {
        int begin = cursor[node];
        int d     = ideg[node];
        int nb    = (d + 15) >> 4;
        float acc[8];
        if (slot == 0) {
            half8 v = *(const half8*)(T + (size_t)node * IN_F + fl * 8);
#pragma unroll
            for (int i = 0; i < 8; ++i) acc[i] = (float)v[i];
        } else {
#pragma unroll
            for (int i = 0; i < 8; ++i) acc[i] = 0.f;
        }
        const int* cp = col + begin + slot;
        int itb = 0;
        for (; itb + 2 <= nb; itb += 2, cp += 32) {
            int s0 = cp[0];
            int s1 = cp[16];
            half8 v0 = *(const half8*)(T + (size_t)s0 * IN_F + fl * 8);
            half8 v1 = *(const half8*)(T + (size_t)s1 * IN_F + fl * 8);
#pragma unroll
            for (int i = 0; i < 8; ++i) acc[i] += (float)v0[i] + (float)v1[i];
        }
        if (itb < nb) {
            int s0 = cp[0];
            half8 v0 = *(const half8*)(T + (size_t)s0 * IN_F + fl * 8);
#pragma unroll
            for (int i = 0; i < 8; ++i) acc[i] += (float)v0[i];
        }
#pragma unroll
        for (int m = 4; m < 64; m <<= 1)
#pragma unroll
            for (int i = 0; i < 8; ++i) acc[i] += __shfl_xor(acc[i], m, 64);
        if (slot == 0) {
            float dis = rsqrtf(1.0f + (float)d);
            half8 o;
#pragma unroll
            for (int i = 0; i < 8; ++i) o[i] = (_Float16)(acc[i] * dis);
            *(half8*)(OUT + (size_t)node * IN_F + fl * 8) = o;
        }
    }
}

// fin: out = relu(acc*dis + b), fp32 out
__global__ __launch_bounds__(256) void k_gather32_fin(
    const int* __restrict__ cursor, const int* __restrict__ ideg,
    const int* __restrict__ col, const _Float16* __restrict__ T,
    const float* __restrict__ b, float* __restrict__ OUT) {
    const int lane = threadIdx.x & 63;
    const int slot = lane >> 2;
    const int fl   = lane & 3;
    const int wid  = blockIdx.x * 4 + (threadIdx.x >> 6);
    const int wstride = gridDim.x * 4;

    float4 bb0 = *(const float4*)(b + fl * 8);
    float4 bb1 = *(const float4*)(b + fl * 8 + 4);
    float bias[8] = {bb0.x, bb0.y, bb0.z, bb0.w, bb1.x, bb1.y, bb1.z, bb1.w};

    for (int node = wid; node < N_NODES; node += wstride) {
        int begin = cursor[node];
        int d     = ideg[node];
        int nb    = (d + 15) >> 4;
        float acc[8];
        if (slot == 0) {
            half8 v = *(const half8*)(T + (size_t)node * IN_F + fl * 8);
#pragma unroll
            for (int i = 0; i < 8; ++i) acc[i] = (float)v[i];
        } else {
#pragma unroll
            for (int i = 0; i < 8; ++i) acc[i] = 0.f;
        }
        const int* cp = col + begin + slot;
        int itb = 0;
        for (; itb + 2 <= nb; itb += 2, cp += 32) {
            int s0 = cp[0];
            int s1 = cp[16];
            half8 v0 = *(const half8*)(T + (size_t)s0 * IN_F + fl * 8);
            half8 v1 = *(const half8*)(T + (size_t)s1 * IN_F + fl * 8);
#pragma unroll
            for (int i = 0; i < 8; ++i) acc[i] += (float)v0[i] + (float)v1[i];
        }
        if (itb < nb) {
            int s0 = cp[0];
            half8 v0 = *(const half8*)(T + (size_t)s0 * IN_F + fl * 8);
#pragma unroll
            for (int i = 0; i < 8; ++i) acc[i] += (float)v0[i];
        }
#pragma unroll
        for (int m = 4; m < 64; m <<= 1)
#pragma unroll
            for (int i = 0; i < 8; ++i) acc[i] += __shfl_xor(acc[i], m, 64);
        if (slot == 0) {
            float dis = rsqrtf(1.0f + (float)d);
            float o[8];
#pragma unroll
            for (int i = 0; i < 8; ++i) {
                float v = acc[i] * dis + bias[i];
                o[i] = v > 0.f ? v : 0.f;
            }
            float* op = OUT + (size_t)node * IN_F + fl * 8;
            *(float4*)op       = make_float4(o[0], o[1], o[2], o[3]);
            *(float4*)(op + 4) = make_float4(o[4], o[5], o[6], o[7]);
        }
    }
}

// 128-dim: 4 slots x 16 feat-lanes. Padded rows -> one int4 col load + 4
// independent 256B row loads in flight per step, no bounds checks.
__global__ __launch_bounds__(256) void k_gather128(
    const int* __restrict__ cursor, const int* __restrict__ ideg,
    const int* __restrict__ col, const _Float16* __restrict__ T,
    const float* __restrict__ b, _Float16* __restrict__ OUT) {
    const int lane = threadIdx.x & 63;
    const int slot = lane >> 4;
    const int fl   = lane & 15;
    const int wid  = blockIdx.x * 4 + (threadIdx.x >> 6);
    const int wstride = gridDim.x * 4;

    float4 bb0 = *(const float4*)(b + fl * 8);
    float4 bb1 = *(const float4*)(b + fl * 8 + 4);
    float bias[8] = {bb0.x, bb0.y, bb0.z, bb0.w, bb1.x, bb1.y, bb1.z, bb1.w};

    for (int node = wid; node < N_NODES; node += wstride) {
        int begin = cursor[node];
        int d     = ideg[node];
        int nb    = (d + 15) >> 4;
        float acc[8];
        if (slot == 0) {
            half8 v = *(const half8*)(T + (size_t)node * HID + fl * 8);
#pragma unroll
            for (int i = 0; i < 8; ++i) acc[i] = (float)v[i];
        } else {
#pragma unroll
            for (int i = 0; i < 8; ++i) acc[i] = 0.f;
        }
        const int* cp = col + begin + slot * 4;   // 16B-aligned (cursor % 16 == 0)
        for (int itb = 0; itb < nb; ++itb, cp += 16) {
            int4 cc = *(const int4*)cp;
            half8 v0 = *(const half8*)(T + (size_t)cc.x * HID + fl * 8);
            half8 v1 = *(const half8*)(T + (size_t)cc.y * HID + fl * 8);
            half8 v2 = *(const half8*)(T + (size_t)cc.z * HID + fl * 8);
            half8 v3 = *(const half8*)(T + (size_t)cc.w * HID + fl * 8);
#pragma unroll
            for (int i = 0; i < 8; ++i)
                acc[i] += ((float)v0[i] + (float)v1[i]) + ((float)v2[i] + (float)v3[i]);
        }
#pragma unroll
        for (int m = 16; m < 64; m <<= 1)
#pragma unroll
            for (int i = 0; i < 8; ++i) acc[i] += __shfl_xor(acc[i], m, 64);
        if (slot == 0) {
            float dis = rsqrtf(1.0f + (float)d);
            half8 o;
#pragma unroll
            for (int i = 0; i < 8; ++i) {
                float v = acc[i] * dis + bias[i];
                o[i] = (_Float16)(v > 0.f ? v : 0.f);
            }
            *(half8*)(OUT + (size_t)node * HID + fl * 8) = o;
        }
    }
}

// ---------------- MFMA transforms ----------------
// 16x16x32 layouts: A[m=lane&15][k=quad*8+j], B[k=quad*8+j][n=lane&15],
// D[row=quad*4+r][col=lane&15]. Block = 4 waves x 16 rows = 64 rows.

// FUSED layers 1+2 transform: T2 = (relu(z·W1 + b1) · W2) · dis, per 64-row block.
// Phase 1 == xform1 (writes H1 tile to LDS); phase 2 == xform2 (reads A from LDS).
__global__ __launch_bounds__(256) void k_xform12_mfma(
    const _Float16* __restrict__ z, const float* __restrict__ W1,
    const float* __restrict__ b1, const float* __restrict__ W2,
    const int* __restrict__ ideg, _Float16* __restrict__ T) {
    // zero row at index N_NODES (128-dim view) for pad gathers in k_gather128
    if (blockIdx.x == 0 && threadIdx.x < 64)
        ((unsigned*)(T + (size_t)N_NODES * HID))[threadIdx.x] = 0u;
    __shared__ _Float16 W1t[128 * 40];    // [n][k] k in [0,32)
    __shared__ _Float16 W2t[128 * 136];   // [n][k] k in [0,128)
    __shared__ _Float16 H1s[64 * 136];    // 64-row H1 tile, stride 136
    for (int idx = threadIdx.x; idx < 2048; idx += 256) {
        int n = idx & 127, k = (idx >> 7) * 2;
        pack2(&W1t[n * 40 + k], W1[k * HID + n], W1[(k + 1) * HID + n]);
    }
    for (int idx = threadIdx.x; idx < 8192; idx += 256) {
        int n = idx & 127, k = (idx >> 7) * 2;
        pack2(&W2t[n * 136 + k], W2[k * HID + n], W2[(k + 1) * HID + n]);
    }
    __syncthreads();

    const int lane = threadIdx.x & 63;
    const int wave = threadIdx.x >> 6;
    const int m16 = lane & 15, quad = lane >> 4;
    const int row0 = blockIdx.x * 64 + wave * 16;
    if (row0 >= N_NODES) return;

    // ---- phase 1: H1 tile = relu(z·W1 + b1)  (rows row0..row0+15) ----
    {
        int arow = row0 + m16; if (arow >= N_NODES) arow = N_NODES - 1;
        half8 a = *(const half8*)(z + (size_t)arow * IN_F + quad * 8);
        floatx4 acc[8];
#pragma unroll
        for (int t = 0; t < 8; ++t) acc[t] = (floatx4){0.f, 0.f, 0.f, 0.f};
#pragma unroll
        for (int t = 0; t < 8; ++t) {
            half8 b = *(const half8*)&W1t[(t * 16 + m16) * 40 + quad * 8];
            acc[t] = __builtin_amdgcn_mfma_f32_16x16x32_f16(a, b, acc[t], 0, 0, 0);
        }
#pragma unroll
        for (int t = 0; t < 8; ++t) {
            int c = t * 16 + m16;
            float bj = b1[c];
#pragma unroll
            for (int r = 0; r < 4; ++r) {
                float v = acc[t][r] + bj;
                H1s[(wave * 16 + quad * 4 + r) * 136 + c] =
                    (_Float16)(v > 0.f ? v : 0.f);
            }
        }
    }
    __syncthreads();

    // ---- phase 2: T2 rows = (H1 · W2) · dis ----
    const _Float16* hp = &H1s[(wave * 16 + m16) * 136 + quad * 8];
    half8 a[4];
#pragma unroll
    for (int kk = 0; kk < 4; ++kk) a[kk] = *(const half8*)(hp + kk * 32);

    floatx4 acc[8];
#pragma unroll
    for (int t = 0; t < 8; ++t) acc[t] = (floatx4){0.f, 0.f, 0.f, 0.f};
#pragma unroll
    for (int t = 0; t < 8; ++t) {
        const _Float16* wp = &W2t[(t * 16 + m16) * 136 + quad * 8];
#pragma unroll
        for (int kk = 0; kk < 4; ++kk) {
            half8 b = *(const half8*)(wp + kk * 32);
            acc[t] = __builtin_amdgcn_mfma_f32_16x16x32_f16(a[kk], b, acc[t], 0, 0, 0);
        }
    }
    float dis[4];
#pragma unroll
    for (int r = 0; r < 4; ++r) {
        int row = row0 + quad * 4 + r;
        dis[r] = (row < N_NODES) ? rsqrtf(1.0f + (float)ideg[row]) : 0.f;
    }
#pragma unroll
    for (int t = 0; t < 8; ++t) {
        int c = t * 16 + m16;
#pragma unroll
        for (int r = 0; r < 4; ++r) {
            int row = row0 + quad * 4 + r;
            if (row < N_NODES)
                T[(size_t)row * HID + c] = (_Float16)(acc[t][r] * dis[r]);
        }
    }
}

__global__ __launch_bounds__(256) void k_xform3_mfma(
    const _Float16* __restrict__ H, const float* __restrict__ W,
    const int* __restrict__ ideg, _Float16* __restrict__ T) {
    // zero row at index N_NODES (32-dim view) for pad gathers in k_gather32_fin
    if (blockIdx.x == 0 && threadIdx.x < 16)
        ((unsigned*)(T + (size_t)N_NODES * IN_F))[threadIdx.x] = 0u;
    __shared__ _Float16 Wt[32 * 136];
    for (int idx = threadIdx.x; idx < 2048; idx += 256) {
        int n = idx & 31, k = (idx >> 5) * 2;
        pack2(&Wt[n * 136 + k], W[k * IN_F + n], W[(k + 1) * IN_F + n]);
    }
    __syncthreads();

    const int lane = threadIdx.x & 63;
    const int wave = threadIdx.x >> 6;
    const int m16 = lane & 15, quad = lane >> 4;
    const int row0 = blockIdx.x * 64 + wave * 16;
    if (row0 >= N_NODES) return;

    int arow = row0 + m16; if (arow >= N_NODES) arow = N_NODES - 1;
    const _Float16* hp = H + (size_t)arow * HID + quad * 8;
    half8 a[4];
#pragma unroll
    for (int kk = 0; kk < 4; ++kk) a[kk] = *(const half8*)(hp + kk * 32);

    floatx4 acc[2];
#pragma unroll
    for (int t = 0; t < 2; ++t) acc[t] = (floatx4){0.f, 0.f, 0.f, 0.f};
#pragma unroll
    for (int t = 0; t < 2; ++t) {
        const _Float16* wp = &Wt[(t * 16 + m16) * 136 + quad * 8];
#pragma unroll
        for (int kk = 0; kk < 4; ++kk) {
            half8 b = *(const half8*)(wp + kk * 32);
            acc[t] = __builtin_amdgcn_mfma_f32_16x16x32_f16(a[kk], b, acc[t], 0, 0, 0);
        }
    }
    float dis[4];
#pragma unroll
    for (int r = 0; r < 4; ++r) {
        int row = row0 + quad * 4 + r;
        dis[r] = (row < N_NODES) ? rsqrtf(1.0f + (float)ideg[row]) : 0.f;
    }
#pragma unroll
    for (int t = 0; t < 2; ++t) {
        int c = t * 16 + m16;
#pragma unroll
        for (int r = 0; r < 4; ++r) {
            int row = row0 + quad * 4 + r;
            if (row < N_NODES)
                T[(size_t)row * IN_F + c] = (_Float16)(acc[t][r] * dis[r]);
        }
    }
}

// ---------------- launch ----------------

extern "C" void kernel_launch(void* const* d_in, const int* in_sizes, int n_in,
                              void* d_out, int out_size, void* d_ws, size_t ws_size,
                              hipStream_t stream) {
    const float* x  = (const float*)d_in[0];
    const int*   ei = (const int*)d_in[1];
    const float* W1 = (const float*)d_in[2];
    const float* b1 = (const float*)d_in[3];
    const float* W2 = (const float*)d_in[4];
    const float* b2 = (const float*)d_in[5];
    const float* W3 = (const float*)d_in[6];
    const float* b3 = (const float*)d_in[7];
    float* out = (float*)d_out;

    const int* src = ei;             // edge_index[0]
    const int* dst = ei + N_EDGES;   // edge_index[1]

    // workspace layout (all offsets 16B-aligned)
    int*      ideg   = (int*)d_ws;                           // N (padded 102400)
    int*      cursor = ideg + 102400;                        // N
    int*      bcnt   = cursor + 102400;                      // 256
    int*      bbase  = bcnt + 256;                           // 256 (197 used)
    int*      bcur   = bbase + 256;                          // 256
    int*      col    = bcur + 256;                           // COLSZ (padded CSR)
    unsigned* rec    = (unsigned*)(col + COLSZ);             // E (dead after k_fill3)
    _Float16* t1h    = (_Float16*)rec;                       // ALIASES rec: (N+pad)*32 fp16
    _Float16* z      = t1h + (size_t)N_NODES * IN_F + 64;    // N*32 fp16
    _Float16* H1h    = z + (size_t)N_NODES * IN_F;           // N*128 fp16 (unused now)
    _Float16* T2h    = H1h + (size_t)N_NODES * HID;          // (N+1)*128 fp16 (reused as T3)
    _Float16* H2h    = T2h + (size_t)N_NODES * HID + 128;    // N*128 fp16

    const int xgrid = (N_NODES + 63) / 64;   // 1563

    // ---- CSR build (bucketed; no global per-node atomics) ----
    hipMemsetAsync(bcnt, 0, 256 * sizeof(int), stream);
    k_bcount<<<NBB, 256, 0, stream>>>(dst, bcnt);
    k_bscan<<<1, 256, 0, stream>>>(bcnt, bbase, bcur);
    k_bucket<<<NBB, 256, 0, stream>>>(src, dst, bcur, rec);
    k_fill3<<<NBUCK, 256, 0, stream>>>(rec, bbase, ideg, cursor, col);

    // ---- layer 1 (aggregate-first; 32-dim gather, then fused MFMA 32->128->128) ----
    k_prescale<<<(N_NODES * 16 + 255) / 256, 256, 0, stream>>>(
        (const float2*)x, ideg, (__half2*)t1h);
    k_gather32_pre<<<2048, 256, 0, stream>>>(cursor, ideg, col, t1h, z);
    k_xform12_mfma<<<xgrid, 256, 0, stream>>>(z, W1, b1, W2, ideg, T2h);

    // ---- layer 2 aggregation (128-dim fp16 gather) ----
    k_gather128<<<2048, 256, 0, stream>>>(cursor, ideg, col, T2h, b2, H2h);

    // ---- layer 3 (MFMA 128->32, then 32-dim gather) ----
    k_xform3_mfma<<<xgrid, 256, 0, stream>>>(H2h, W3, ideg, T2h);
    k_gather32_fin<<<2048, 256, 0, stream>>>(cursor, ideg, col, T2h, b3, out);
}

// Round 6
// 323.866 us; speedup vs baseline: 8.8417x; 1.0162x over previous
//
#include <hip/hip_runtime.h>
#include <hip/hip_fp16.h>

#define N_NODES 100000
#define N_EDGES 1600000
#define IN_F 32
#define HID 128
#define BSHIFT 9
#define BSIZE 512
#define NBUCK 196        // ceil(100000/512)
#define EPB 4096         // edges per bucket-phase block
#define NBB 391          // ceil(E/EPB)
#define REC_STRIDE 9728  // per-bucket rec capacity (mean 8192 + 17 sigma)
#define COL_STRIDE 17408 // REC_STRIDE + 7680 (worst pad); multiple of 16

typedef _Float16 half8 __attribute__((ext_vector_type(8)));
typedef float floatx4 __attribute__((ext_vector_type(4)));

// ---------------- weight pre-transpose: W*t[n][k] fp16 in global ----------------
// Wt layout: W1t [128][32] @ 0, W2t [128][128] @ 4096, W3t [32][128] @ 20480
__global__ __launch_bounds__(256) void k_wprep(const float* __restrict__ W1,
                                               const float* __restrict__ W2,
                                               const float* __restrict__ W3,
                                               _Float16* __restrict__ Wt) {
    const int bid = blockIdx.x, t = threadIdx.x;
    if (bid < 64) {               // W2: 16384 elems
        int idx = bid * 256 + t;
        int n = idx >> 7, k = idx & 127;
        Wt[4096 + idx] = (_Float16)W2[k * HID + n];
    } else if (bid < 80) {        // W1: 4096 elems
        int idx = (bid - 64) * 256 + t;
        int n = idx >> 5, k = idx & 31;
        Wt[n * 32 + k] = (_Float16)W1[k * HID + n];
    } else {                      // W3: 4096 elems
        int idx = (bid - 80) * 256 + t;
        int n = idx >> 7, k = idx & 127;
        Wt[20480 + idx] = (_Float16)W3[k * IN_F + n];
    }
}

// ---------------- CSR build (static bucket regions; no count/scan kernels) -------

__global__ __launch_bounds__(256) void k_bucket(const int* __restrict__ src,
                                                const int* __restrict__ dst,
                                                int* __restrict__ bcur,
                                                unsigned* __restrict__ rec) {
    __shared__ int hist[256];
    __shared__ int lbase[256];
    const int e0 = blockIdx.x * EPB;
    hist[threadIdx.x] = 0;
    __syncthreads();

    unsigned rk[16]; short bk[16];
#pragma unroll
    for (int k = 0; k < 16; ++k) {
        int e = e0 + k * 256 + threadIdx.x;
        if (e < N_EDGES) {
            int d = dst[e];
            int b = d >> BSHIFT;
            bk[k] = (short)b;
            rk[k] = ((unsigned)src[e] << BSHIFT) | (unsigned)(d & (BSIZE - 1));
            atomicAdd(&hist[b], 1);
        } else bk[k] = -1;
    }
    __syncthreads();
    int c = hist[threadIdx.x];
    lbase[threadIdx.x] =
        (c > 0) ? threadIdx.x * REC_STRIDE + atomicAdd(&bcur[threadIdx.x], c) : 0;
    __syncthreads();
    hist[threadIdx.x] = 0;   // reuse as local running offset
    __syncthreads();
#pragma unroll
    for (int k = 0; k < 16; ++k) {
        if (bk[k] >= 0) {
            int off = atomicAdd(&hist[bk[k]], 1);
            rec[lbase[bk[k]] + off] = rk[k];
        }
    }
}

// per bucket: degree count + PADDED scan (rows padded to mult of 16, pads -> zero
// row N_NODES), col scatter, AND fused prescale t1 = x * dis (fp16).
__global__ __launch_bounds__(256) void k_fill3p(const unsigned* __restrict__ rec,
                                                const int* __restrict__ bcur,
                                                const float2* __restrict__ x2,
                                                int* __restrict__ ideg,
                                                int* __restrict__ cursor,
                                                int* __restrict__ col,
                                                __half2* __restrict__ t1) {
    __shared__ int lcnt[BSIZE];
    __shared__ int lcur[BSIZE];
    __shared__ int lend[BSIZE];
    __shared__ int s[256];
    const int b = blockIdx.x;
    const int t = threadIdx.x;
    const int n0 = b << BSHIFT;
    const int rbeg = b * REC_STRIDE;
    const int rend = rbeg + bcur[b];
    const int pbeg = b * COL_STRIDE;   // 16-aligned

    lcnt[t] = 0;
    lcnt[t + 256] = 0;
    __syncthreads();
    for (int i = rbeg + t; i < rend; i += 256)
        atomicAdd(&lcnt[rec[i] & (BSIZE - 1)], 1);
    __syncthreads();

    int a0 = lcnt[2 * t], a1 = lcnt[2 * t + 1];
    int p0 = (a0 + 15) & ~15, p1 = (a1 + 15) & ~15;
    int pv = p0 + p1;
    s[t] = pv;
    __syncthreads();
    for (int off = 1; off < 256; off <<= 1) {
        int v = (t >= off) ? s[t - off] : 0;
        __syncthreads();
        s[t] += v;
        __syncthreads();
    }
    int ex = s[t] - pv;
    int c0 = pbeg + ex;
    int c1 = c0 + p0;
    lcur[2 * t]     = c0;  lend[2 * t]     = c0 + p0;
    lcur[2 * t + 1] = c1;  lend[2 * t + 1] = c1 + p1;
    __syncthreads();

    for (int i = t; i < BSIZE; i += 256) {
        int n = n0 + i;
        if (n < N_NODES) {
            ideg[n]   = lcnt[i];
            cursor[n] = lcur[i];
        }
    }
    __syncthreads();
    for (int i = rbeg + t; i < rend; i += 256) {
        unsigned r = rec[i];
        int slot = atomicAdd(&lcur[r & (BSIZE - 1)], 1);
        col[slot] = (int)(r >> BSHIFT);
    }
    __syncthreads();
    for (int i = t; i < BSIZE; i += 256) {
        int e2 = lend[i];
        for (int k = lcur[i]; k < e2; ++k) col[k] = N_NODES;
    }

    // fused prescale for this bucket's 512 nodes (+ zero row by block 0)
    if (b == 0 && t < 16) ((unsigned*)t1)[N_NODES * 16 + t] = 0u;
    for (int idx = t; idx < BSIZE * 16; idx += 256) {
        int loc = idx >> 4, j = idx & 15;
        int n = n0 + loc;
        if (n < N_NODES) {
            float dis = rsqrtf(1.0f + (float)lcnt[loc]);
            float2 v = x2[(size_t)n * 16 + j];
            t1[(size_t)n * 16 + j] = __floats2half2_rn(v.x * dis, v.y * dis);
        }
    }
}

// ---------------- gathers (branch-free padded CSR, static partition) ----------------

// pre: z = acc*dis, fp16 out. 16 slots x 4 feat-lanes, x2-deep pipeline.
__global__ __launch_bounds__(256) void k_gather32_pre(
    const int* __restrict__ cursor, const int* __restrict__ ideg,
    const int* __restrict__ col, const _Float16* __restrict__ T,
    _Float16* __restrict__ OUT) {
    const int lane = threadIdx.x & 63;
    const int slot = lane >> 2;
    const int fl   = lane & 3;
    const int wid  = blockIdx.x * 4 + (threadIdx.x >> 6);
    const int wstride = gridDim.x * 4;

    for (int node = wid; node < N_NODES; node += wstride) {
        int begin = cursor[node];
        int d     = ideg[node];
        int nb    = (d + 15) >> 4;
        float acc[8];
        if (slot == 0) {
            half8 v = *(const half8*)(T + (size_t)node * IN_F + fl * 8);
#pragma unroll
            for (int i = 0; i < 8; ++i) acc[i] = (float)v[i];
        } else {
#pragma unroll
            for (int i = 0; i < 8; ++i) acc[i] = 0.f;
        }
        const int* cp = col + begin + slot;
        int itb = 0;
        for (; itb + 2 <= nb; itb += 2, cp += 32) {
            int s0 = cp[0];
            int s1 = cp[16];
            half8 v0 = *(const half8*)(T + (size_t)s0 * IN_F + fl * 8);
            half8 v1 = *(const half8*)(T + (size_t)s1 * IN_F + fl * 8);
#pragma unroll
            for (int i = 0; i < 8; ++i) acc[i] += (float)v0[i] + (float)v1[i];
        }
        if (itb < nb) {
            int s0 = cp[0];
            half8 v0 = *(const half8*)(T + (size_t)s0 * IN_F + fl * 8);
#pragma unroll
            for (int i = 0; i < 8; ++i) acc[i] += (float)v0[i];
        }
#pragma unroll
        for (int m = 4; m < 64; m <<= 1)
#pragma unroll
            for (int i = 0; i < 8; ++i) acc[i] += __shfl_xor(acc[i], m, 64);
        if (slot == 0) {
            float dis = rsqrtf(1.0f + (float)d);
            half8 o;
#pragma unroll
            for (int i = 0; i < 8; ++i) o[i] = (_Float16)(acc[i] * dis);
            *(half8*)(OUT + (size_t)node * IN_F + fl * 8) = o;
        }
    }
}

// fin: out = relu(acc*dis + b), fp32 out
__global__ __launch_bounds__(256) void k_gather32_fin(
    const int* __restrict__ cursor, const int* __restrict__ ideg,
    const int* __restrict__ col, const _Float16* __restrict__ T,
    const float* __restrict__ b, float* __restrict__ OUT) {
    const int lane = threadIdx.x & 63;
    const int slot = lane >> 2;
    const int fl   = lane & 3;
    const int wid  = blockIdx.x * 4 + (threadIdx.x >> 6);
    const int wstride = gridDim.x * 4;

    float4 bb0 = *(const float4*)(b + fl * 8);
    float4 bb1 = *(const float4*)(b + fl * 8 + 4);
    float bias[8] = {bb0.x, bb0.y, bb0.z, bb0.w, bb1.x, bb1.y, bb1.z, bb1.w};

    for (int node = wid; node < N_NODES; node += wstride) {
        int begin = cursor[node];
        int d     = ideg[node];
        int nb    = (d + 15) >> 4;
        float acc[8];
        if (slot == 0) {
            half8 v = *(const half8*)(T + (size_t)node * IN_F + fl * 8);
#pragma unroll
            for (int i = 0; i < 8; ++i) acc[i] = (float)v[i];
        } else {
#pragma unroll
            for (int i = 0; i < 8; ++i) acc[i] = 0.f;
        }
        const int* cp = col + begin + slot;
        int itb = 0;
        for (; itb + 2 <= nb; itb += 2, cp += 32) {
            int s0 = cp[0];
            int s1 = cp[16];
            half8 v0 = *(const half8*)(T + (size_t)s0 * IN_F + fl * 8);
            half8 v1 = *(const half8*)(T + (size_t)s1 * IN_F + fl * 8);
#pragma unroll
            for (int i = 0; i < 8; ++i) acc[i] += (float)v0[i] + (float)v1[i];
        }
        if (itb < nb) {
            int s0 = cp[0];
            half8 v0 = *(const half8*)(T + (size_t)s0 * IN_F + fl * 8);
#pragma unroll
            for (int i = 0; i < 8; ++i) acc[i] += (float)v0[i];
        }
#pragma unroll
        for (int m = 4; m < 64; m <<= 1)
#pragma unroll
            for (int i = 0; i < 8; ++i) acc[i] += __shfl_xor(acc[i], m, 64);
        if (slot == 0) {
            float dis = rsqrtf(1.0f + (float)d);
            float o[8];
#pragma unroll
            for (int i = 0; i < 8; ++i) {
                float v = acc[i] * dis + bias[i];
                o[i] = v > 0.f ? v : 0.f;
            }
            float* op = OUT + (size_t)node * IN_F + fl * 8;
            *(float4*)op       = make_float4(o[0], o[1], o[2], o[3]);
            *(float4*)(op + 4) = make_float4(o[4], o[5], o[6], o[7]);
        }
    }
}

// ---------------- MFMA transforms ----------------
// 16x16x32 layouts: A[m=lane&15][k=quad*8+j], B[k=quad*8+j][n=lane&15],
// D[row=quad*4+r][col=lane&15]. Block = 4 waves x 16 rows = 64 rows.

// FUSED layers 1+2 transform: T2 = (relu(z·W1 + b1) · W2) · dis.
// Weights read as fragments from pre-transposed global (L1/L2-hot); LDS = H1 tile only.
__global__ __launch_bounds__(256, 4) void k_xform12(
    const _Float16* __restrict__ z, const _Float16* __restrict__ W1t,
    const float* __restrict__ b1, const _Float16* __restrict__ W2t,
    const int* __restrict__ ideg, _Float16* __restrict__ T) {
    if (blockIdx.x == 0 && threadIdx.x < 64)
        ((unsigned*)(T + (size_t)N_NODES * HID))[threadIdx.x] = 0u;
    __shared__ _Float16 H1s[64 * 136];

    const int lane = threadIdx.x & 63;
    const int wave = threadIdx.x >> 6;
    const int m16 = lane & 15, quad = lane >> 4;
    const int row0 = blockIdx.x * 64 + wave * 16;
    if (row0 >= N_NODES) return;

    // phase 1: H1 tile = relu(z·W1 + b1)
    {
        int arow = row0 + m16; if (arow >= N_NODES) arow = N_NODES - 1;
        half8 a = *(const half8*)(z + (size_t)arow * IN_F + quad * 8);
        floatx4 acc[8];
#pragma unroll
        for (int t = 0; t < 8; ++t) acc[t] = (floatx4){0.f, 0.f, 0.f, 0.f};
#pragma unroll
        for (int t = 0; t < 8; ++t) {
            half8 bf = *(const half8*)(W1t + (t * 16 + m16) * 32 + quad * 8);
            acc[t] = __builtin_amdgcn_mfma_f32_16x16x32_f16(a, bf, acc[t], 0, 0, 0);
        }
#pragma unroll
        for (int t = 0; t < 8; ++t) {
            int c = t * 16 + m16;
            float bj = b1[c];
#pragma unroll
            for (int r = 0; r < 4; ++r) {
                float v = acc[t][r] + bj;
                H1s[((wave * 16 + quad * 4 + r) * 136) + c] =
                    (_Float16)(v > 0.f ? v : 0.f);
            }
        }
    }
    __syncthreads();

    // phase 2: T2 rows = (H1 · W2) · dis
    const _Float16* hp = &H1s[(wave * 16 + m16) * 136 + quad * 8];
    half8 a[4];
#pragma unroll
    for (int kk = 0; kk < 4; ++kk) a[kk] = *(const half8*)(hp + kk * 32);

    floatx4 acc[8];
#pragma unroll
    for (int t = 0; t < 8; ++t) acc[t] = (floatx4){0.f, 0.f, 0.f, 0.f};
#pragma unroll
    for (int t = 0; t < 8; ++t) {
        const _Float16* wp = W2t + (t * 16 + m16) * 128 + quad * 8;
#pragma unroll
        for (int kk = 0; kk < 4; ++kk) {
            half8 bf = *(const half8*)(wp + kk * 32);
            acc[t] = __builtin_amdgcn_mfma_f32_16x16x32_f16(a[kk], bf, acc[t], 0, 0, 0);
        }
    }
    float dis[4];
#pragma unroll
    for (int r = 0; r < 4; ++r) {
        int row = row0 + quad * 4 + r;
        dis[r] = (row < N_NODES) ? rsqrtf(1.0f + (float)ideg[row]) : 0.f;
    }
#pragma unroll
    for (int t = 0; t < 8; ++t) {
        int c = t * 16 + m16;
#pragma unroll
        for (int r = 0; r < 4; ++r) {
            int row = row0 + quad * 4 + r;
            if (row < N_NODES)
                T[(size_t)row * HID + c] = (_Float16)(acc[t][r] * dis[r]);
        }
    }
}

// FUSED gather128 + xform3: per 64-node tile, gather H2 rows (relu(acc*dis+b2))
// into LDS, then T3 = (H2 · W3) · dis. Deletes the 51 MB H2 round-trip.
__global__ __launch_bounds__(256, 4) void k_g128x3(
    const int* __restrict__ cursor, const int* __restrict__ ideg,
    const int* __restrict__ col, const _Float16* __restrict__ T,
    const float* __restrict__ b2, const _Float16* __restrict__ W3t,
    _Float16* __restrict__ T3) {
    if (blockIdx.x == 0 && threadIdx.x < 16)
        ((unsigned*)(T3 + (size_t)N_NODES * IN_F))[threadIdx.x] = 0u;
    __shared__ _Float16 H2s[64 * 136];

    const int lane = threadIdx.x & 63;
    const int wave = threadIdx.x >> 6;
    const int slot = lane >> 4;      // == quad
    const int fl   = lane & 15;      // == m16
    const int row0 = blockIdx.x * 64;

    float4 bb0 = *(const float4*)(b2 + fl * 8);
    float4 bb1 = *(const float4*)(b2 + fl * 8 + 4);
    float bias[8] = {bb0.x, bb0.y, bb0.z, bb0.w, bb1.x, bb1.y, bb1.z, bb1.w};

    // gather phase: wave w handles local rows [w*16, w*16+16)
    for (int k = 0; k < 16; ++k) {
        int node = row0 + wave * 16 + k;
        if (node >= N_NODES) break;
        int begin = cursor[node];
        int d     = ideg[node];
        int nb    = (d + 15) >> 4;
        float acc[8];
        if (slot == 0) {
            half8 v = *(const half8*)(T + (size_t)node * HID + fl * 8);
#pragma unroll
            for (int i = 0; i < 8; ++i) acc[i] = (float)v[i];
        } else {
#pragma unroll
            for (int i = 0; i < 8; ++i) acc[i] = 0.f;
        }
        const int* cp = col + begin + slot * 4;   // 16B-aligned
        for (int itb = 0; itb < nb; ++itb, cp += 16) {
            int4 cc = *(const int4*)cp;
            half8 v0 = *(const half8*)(T + (size_t)cc.x * HID + fl * 8);
            half8 v1 = *(const half8*)(T + (size_t)cc.y * HID + fl * 8);
            half8 v2 = *(const half8*)(T + (size_t)cc.z * HID + fl * 8);
            half8 v3 = *(const half8*)(T + (size_t)cc.w * HID + fl * 8);
#pragma unroll
            for (int i = 0; i < 8; ++i)
                acc[i] += ((float)v0[i] + (float)v1[i]) + ((float)v2[i] + (float)v3[i]);
        }
#pragma unroll
        for (int m = 16; m < 64; m <<= 1)
#pragma unroll
            for (int i = 0; i < 8; ++i) acc[i] += __shfl_xor(acc[i], m, 64);
        if (slot == 0) {
            float dis = rsqrtf(1.0f + (float)d);
            half8 o;
#pragma unroll
            for (int i = 0; i < 8; ++i) {
                float v = acc[i] * dis + bias[i];
                o[i] = (_Float16)(v > 0.f ? v : 0.f);
            }
            *(half8*)&H2s[(wave * 16 + k) * 136 + fl * 8] = o;
        }
    }
    __syncthreads();

    // xform3 phase: T3 rows = (H2 · W3) · dis   (m16 = fl, quad = slot)
    const _Float16* hp = &H2s[(wave * 16 + fl) * 136 + slot * 8];
    half8 a[4];
#pragma unroll
    for (int kk = 0; kk < 4; ++kk) a[kk] = *(const half8*)(hp + kk * 32);

    floatx4 acc3[2];
#pragma unroll
    for (int t = 0; t < 2; ++t) acc3[t] = (floatx4){0.f, 0.f, 0.f, 0.f};
#pragma unroll
    for (int t = 0; t < 2; ++t) {
        const _Float16* wp = W3t + (t * 16 + fl) * 128 + slot * 8;
#pragma unroll
        for (int kk = 0; kk < 4; ++kk) {
            half8 bf = *(const half8*)(wp + kk * 32);
            acc3[t] = __builtin_amdgcn_mfma_f32_16x16x32_f16(a[kk], bf, acc3[t], 0, 0, 0);
        }
    }
    float dis[4];
#pragma unroll
    for (int r = 0; r < 4; ++r) {
        int row = row0 + wave * 16 + slot * 4 + r;
        dis[r] = (row < N_NODES) ? rsqrtf(1.0f + (float)ideg[row]) : 0.f;
    }
#pragma unroll
    for (int t = 0; t < 2; ++t) {
        int c = t * 16 + fl;
#pragma unroll
        for (int r = 0; r < 4; ++r) {
            int row = row0 + wave * 16 + slot * 4 + r;
            if (row < N_NODES)
                T3[(size_t)row * IN_F + c] = (_Float16)(acc3[t][r] * dis[r]);
        }
    }
}

// ---------------- launch ----------------

extern "C" void kernel_launch(void* const* d_in, const int* in_sizes, int n_in,
                              void* d_out, int out_size, void* d_ws, size_t ws_size,
                              hipStream_t stream) {
    const float* x  = (const float*)d_in[0];
    const int*   ei = (const int*)d_in[1];
    const float* W1 = (const float*)d_in[2];
    const float* b1 = (const float*)d_in[3];
    const float* W2 = (const float*)d_in[4];
    const float* b2 = (const float*)d_in[5];
    const float* W3 = (const float*)d_in[6];
    const float* b3 = (const float*)d_in[7];
    float* out = (float*)d_out;

    const int* src = ei;             // edge_index[0]
    const int* dst = ei + N_EDGES;   // edge_index[1]

    // workspace layout (all offsets 16B-aligned); total ~67 MB
    int*      ideg   = (int*)d_ws;                             // 102400
    int*      cursor = ideg + 102400;                          // 102400
    int*      bcur   = cursor + 102400;                        // 256
    int*      col    = bcur + 256;                             // 196*17408
    unsigned* rec    = (unsigned*)(col + NBUCK * COL_STRIDE);  // 196*9728
    _Float16* Wt     = (_Float16*)(rec + NBUCK * REC_STRIDE);  // 24576 fp16
    _Float16* t1h    = Wt + 24576;                             // (N+1)*32 fp16
    _Float16* z      = t1h + 3200064;                          // N*32 fp16
    _Float16* T2h    = z + 3200064;                            // (N+1)*128 fp16
    _Float16* T3h    = T2h + 12800128;                         // (N+1)*32 fp16

    const int xgrid = (N_NODES + 63) / 64;   // 1563

    hipMemsetAsync(bcur, 0, 256 * sizeof(int), stream);
    k_wprep<<<96, 256, 0, stream>>>(W1, W2, W3, Wt);

    // ---- CSR build ----
    k_bucket<<<NBB, 256, 0, stream>>>(src, dst, bcur, rec);
    k_fill3p<<<NBUCK, 256, 0, stream>>>(rec, bcur, (const float2*)x,
                                        ideg, cursor, col, (__half2*)t1h);

    // ---- layer 1: 32-dim gather, then fused MFMA 32->128->128 ----
    k_gather32_pre<<<2048, 256, 0, stream>>>(cursor, ideg, col, t1h, z);
    k_xform12<<<xgrid, 256, 0, stream>>>(z, Wt, b1, Wt + 4096, ideg, T2h);

    // ---- layer 2+3a: fused 128-dim gather + MFMA 128->32 ----
    k_g128x3<<<xgrid, 256, 0, stream>>>(cursor, ideg, col, T2h, b2,
                                        Wt + 20480, T3h);

    // ---- layer 3b: final 32-dim gather ----
    k_gather32_fin<<<2048, 256, 0, stream>>>(cursor, ideg, col, T3h, b3, out);
}